// Round 5
// baseline (342.894 us; speedup 1.0000x reference)
//
#include <hip/hip_runtime.h>

// Deterministic hard voxelization (mmcv hard_voxelize_forward) for MI355X.
//
// v4: IB=8 batched CAS in k_insert (MLP); exact Lmax pruning removes ~94%
// of k_bucket's random rank gathers (rank(L)<MAXV  <=>  L<=Lmax since
// leader ranks are assigned in increasing first-index order).
//
// Pipeline:
//   K1  k_insert : point -> voxel -> single u64 CAS claim {lin,i}; same-key
//                  -> u64-CAS min loop. hslot[i] = final slot.
//   K2a k_scan1  : lead[i] = entry minidx (random gather, 1 per point);
//                  leader flag = (lead[i]==i); block sums.
//   K2b k_scan2  : single-block exclusive scan of block sums; voxel_num;
//                  Lmax=INT_MAX if total<MAXV.
//   K2c k_scan3  : leaders from lead[i]==i (streaming); rank r per leader
//                  written over hslot[i]; r<MAXV: gather key, write coors;
//                  r==MAXV-1: Lmax=i.
//   K3  k_bucket : L=lead[i]; skip unless L<=Lmax; r=rank[L]; append i.
//   K4  k_emit   : 32 lanes/slot: rank-select by original index, write all
//                  32 rows (zero-fill) + num_points.
//
// Output (float32): voxels[120000*32*4] | coors[120000*3] | npts[120000] | voxel_num[1]

#define GX 1408
#define GY 1600
#define GZ 40
#define MAXV 120000
#define MAXP 32
#define HBITS 22
#define HSIZE (1u << HBITS)      // 4,194,304 slots; ~1.98M keys -> load 0.47
#define HMASK (HSIZE - 1u)
#define ITEMS 16
#define SCAN_BS 256
#define CHUNK (SCAN_BS * ITEMS)  // 4096 points per scan block
#define IB 8                     // points per thread in insert
#define BB 4                     // points per thread in bucket
#define EMIT_SPB 8               // 8 slots x 32 lanes = 256 threads

typedef unsigned long long u64;
typedef unsigned int u32;
#define EMPTY64 0xFFFFFFFFFFFFFFFFull

__device__ __forceinline__ u32 hash_lin(int lin) {
  u32 h = (u32)lin * 2654435761u;
  h ^= h >> 15;
  return h & HMASK;
}

__global__ __launch_bounds__(256) void k_insert(const float4* __restrict__ pts,
                                                u64* __restrict__ ent,
                                                int* __restrict__ hslot, int n) {
  int base = blockIdx.x * (256 * IB) + threadIdx.x;
  int lin[IB]; u32 h[IB]; bool ok[IB]; u64 old[IB];

  // Phase 1: voxel coords (must match JAX f32 ops bit-exactly; no fast-math).
#pragma unroll
  for (int j = 0; j < IB; ++j) {
    int i = base + j * 256;
    ok[j] = false;
    lin[j] = 0; h[j] = 0;
    if (i < n) {
      float4 p = pts[i];
      int cx = (int)floorf((p.x - 0.0f)   / 0.05f);
      int cy = (int)floorf((p.y - -40.0f) / 0.05f);
      int cz = (int)floorf((p.z - -3.0f)  / 0.1f);
      if ((cx >= 0) && (cx < GX) && (cy >= 0) && (cy < GY) && (cz >= 0) && (cz < GZ)) {
        lin[j] = cz * (GX * GY) + cy * GX + cx;
        h[j] = hash_lin(lin[j]);
        ok[j] = true;
      }
    }
  }

  // Phase 2: optimistic first CAS for all IB points back-to-back (MLP).
#pragma unroll
  for (int j = 0; j < IB; ++j) {
    if (ok[j]) {
      u64 des = ((u64)(u32)lin[j] << 32) | (u32)(base + j * 256);
      old[j] = atomicCAS(&ent[h[j]], EMPTY64, des);
    }
  }

  // Phase 3: resolve (rare probe continuation / same-key min).
#pragma unroll
  for (int j = 0; j < IB; ++j) {
    int i = base + j * 256;
    if (i >= n) continue;
    if (!ok[j]) { hslot[i] = -1; continue; }
    u32 i_u = (u32)i;
    u64 des = ((u64)(u32)lin[j] << 32) | i_u;
    u32 hh = h[j];
    u64 o = old[j];
    while (true) {
      if (o == EMPTY64) break;                    // claimed; minidx=i already
      if ((u32)(o >> 32) == (u32)lin[j]) {        // same key: CAS-min low word
        while ((u32)o > i_u) {
          u64 want = (o & 0xFFFFFFFF00000000ull) | (u64)i_u;
          u64 prev = atomicCAS(&ent[hh], o, want);
          if (prev == o) break;
          o = prev;
        }
        break;
      }
      hh = (hh + 1) & HMASK;                      // occupied by other key: probe on
      o = atomicCAS(&ent[hh], EMPTY64, des);
    }
    hslot[i] = (int)hh;
  }
}

__global__ __launch_bounds__(SCAN_BS) void k_scan1(const int* __restrict__ hslot,
                                                   const u32* __restrict__ entw,
                                                   int* __restrict__ lead,
                                                   int* __restrict__ blocksums, int n) {
  __shared__ int sm[SCAN_BS];
  int base = blockIdx.x * CHUNK + threadIdx.x * ITEMS;
  int cnt = 0;
#pragma unroll
  for (int j = 0; j < ITEMS; ++j) {
    int i = base + j;
    if (i < n) {
      int h = hslot[i];
      int L = -1;
      if (h >= 0) L = (int)entw[2u * (u32)h];     // low word = final min index
      lead[i] = L;
      if (L == i) cnt++;
    }
  }
  sm[threadIdx.x] = cnt;
  __syncthreads();
  for (int off = SCAN_BS / 2; off > 0; off >>= 1) {
    if (threadIdx.x < off) sm[threadIdx.x] += sm[threadIdx.x + off];
    __syncthreads();
  }
  if (threadIdx.x == 0) blocksums[blockIdx.x] = sm[0];
}

// Single block of 512 threads: exclusive scan of <=512 block sums.
__global__ __launch_bounds__(512) void k_scan2(int* __restrict__ blocksums,
                                               float* __restrict__ voxnum_out,
                                               int* __restrict__ lmax, int nb) {
  __shared__ int sm[512];
  int t = threadIdx.x;
  int v = (t < nb) ? blocksums[t] : 0;
  sm[t] = v;
  __syncthreads();
  for (int off = 1; off < 512; off <<= 1) {
    int x = sm[t];
    int add = (t >= off) ? sm[t - off] : 0;
    __syncthreads();
    sm[t] = x + add;
    __syncthreads();
  }
  if (t < nb) blocksums[t] = sm[t] - v;  // exclusive block offsets
  if (t == 511) {
    int total = sm[511];
    *voxnum_out = (float)(total < MAXV ? total : MAXV);
    if (total < MAXV) *lmax = 0x7FFFFFFF;  // keep-all; else scan3's rank MAXV-1 leader writes
  }
}

// Leaders from lead[i]==i (streaming). rank written over hslot (aliased).
__global__ __launch_bounds__(SCAN_BS) void k_scan3(const int* __restrict__ lead,
                                                   int* __restrict__ hslot_rank,
                                                   const u32* __restrict__ entw,
                                                   const int* __restrict__ blockoffs,
                                                   float* __restrict__ out_coors,
                                                   int* __restrict__ lmax, int n) {
  __shared__ int sm[SCAN_BS];
  int base = blockIdx.x * CHUNK + threadIdx.x * ITEMS;
  u32 mbits = 0;
  int cnt = 0;
#pragma unroll
  for (int j = 0; j < ITEMS; ++j) {
    int i = base + j;
    if (i < n && lead[i] == i) { mbits |= (1u << j); cnt++; }
  }
  sm[threadIdx.x] = cnt;
  __syncthreads();
  for (int off = 1; off < SCAN_BS; off <<= 1) {  // Hillis-Steele inclusive
    int x = sm[threadIdx.x];
    int add = (threadIdx.x >= off) ? sm[threadIdx.x - off] : 0;
    __syncthreads();
    sm[threadIdx.x] = x + add;
    __syncthreads();
  }
  int r = blockoffs[blockIdx.x] + (sm[threadIdx.x] - cnt);  // exclusive rank
#pragma unroll
  for (int j = 0; j < ITEMS; ++j) {
    if (mbits & (1u << j)) {
      int i = base + j;
      int h = hslot_rank[i];       // read slot BEFORE overwriting with rank
      hslot_rank[i] = r;
      if (r == MAXV - 1) *lmax = i;  // unique writer: last kept leader's first-index
      if (r < MAXV) {
        int lin = (int)entw[2u * (u32)h + 1u];   // high word = key
        int x = lin % GX;
        int t = lin / GX;
        int y = t % GY;
        int z = t / GY;
        out_coors[r * 3 + 0] = (float)z;
        out_coors[r * 3 + 1] = (float)y;
        out_coors[r * 3 + 2] = (float)x;
      }
      r++;
    }
  }
}

__global__ __launch_bounds__(256) void k_bucket(const int* __restrict__ lead,
                                                const int* __restrict__ rank,
                                                const int* __restrict__ lmax,
                                                int* __restrict__ bcnt,
                                                int* __restrict__ bucket, int n) {
  int Lmax = *lmax;  // broadcast scalar load (same line for all blocks)
  int base = blockIdx.x * (256 * BB) + threadIdx.x;
#pragma unroll
  for (int j = 0; j < BB; ++j) {
    int i = base + j * 256;
    if (i < n) {
      int L = lead[i];
      // rank(L) < MAXV  <=>  L <= Lmax  (ranks increase with first-index).
      if (L >= 0 && L <= Lmax) {
        int r = rank[L];
        if (r < MAXV) {           // redundant safety; always true given prune
          int pos = atomicAdd(&bcnt[r], 1);
          if (pos < MAXP) bucket[r * MAXP + pos] = i;
        }
      }
    }
  }
}

// 32 lanes per slot. Lane r rank-selects the bucket entry of rank r
// (ascending original index) and writes voxels[s][r]; zero-fill the rest.
// Writes fully coalesced: lane r stores 16B at (s*32+r)*16.
__global__ __launch_bounds__(256) void k_emit(const float4* __restrict__ pts,
                                              const int* __restrict__ bcnt,
                                              const int* __restrict__ bucket,
                                              float4* __restrict__ out_voxels,
                                              float* __restrict__ out_npts) {
  __shared__ int sb[EMIT_SPB][MAXP];
  int grp = threadIdx.x >> 5;
  int r = threadIdx.x & 31;
  int s = blockIdx.x * EMIT_SPB + grp;
  if (s >= MAXV) return;

  int nfull = bcnt[s];
  int m = nfull < MAXP ? nfull : MAXP;
  if (r < m) sb[grp][r] = bucket[s * MAXP + r];
  __syncthreads();

  float4 row = make_float4(0.f, 0.f, 0.f, 0.f);
  if (r < m) {
    int mine = -1;
    for (int jj = 0; jj < m; ++jj) {   // entries unique; find rank==r
      int ej = sb[grp][jj];
      int rk = 0;
      for (int kk = 0; kk < m; ++kk) rk += (sb[grp][kk] < ej) ? 1 : 0;
      if (rk == r) mine = ej;
    }
    row = pts[mine];
  }
  out_voxels[(size_t)s * MAXP + r] = row;
  if (r == 0) out_npts[s] = (float)m;
}

extern "C" void kernel_launch(void* const* d_in, const int* in_sizes, int n_in,
                              void* d_out, int out_size, void* d_ws, size_t ws_size,
                              hipStream_t stream) {
  const float4* pts = (const float4*)d_in[0];
  int n = in_sizes[0] / 4;  // 2,000,000
  float* out = (float*)d_out;

  // Workspace layout (bytes); total ~63.9 MB
  char* ws = (char*)d_ws;
  u64* ent       = (u64*)(ws);                                    // 32 MB
  int* hslot     = (int*)(ws + (size_t)HSIZE * 8);                // 8 MB (becomes rank)
  int* lead      = (int*)(ws + (size_t)HSIZE * 8 + (size_t)n * 4);           // 8 MB
  int* blocksums = (int*)(ws + (size_t)HSIZE * 8 + (size_t)n * 8);           // 16 KB
  int* lmax      = (int*)(ws + (size_t)HSIZE * 8 + (size_t)n * 8 + 16000);   // 4 B (inside 16KB pad)
  int* bcnt      = (int*)(ws + (size_t)HSIZE * 8 + (size_t)n * 8 + 16384);   // 480 KB
  int* bucket    = (int*)(ws + (size_t)HSIZE * 8 + (size_t)n * 8 + 16384 + (size_t)MAXV * 4);  // 15.36 MB

  float* out_voxels = out;                                     // 120000*32*4
  float* out_coors  = out + (size_t)MAXV * MAXP * 4;           // 120000*3
  float* out_npts   = out_coors + (size_t)MAXV * 3;            // 120000
  float* out_voxnum = out_npts + MAXV;                         // 1

  hipMemsetAsync(ent, 0xFF, (size_t)HSIZE * 8, stream);        // EMPTY64 everywhere
  hipMemsetAsync(bcnt, 0, (size_t)MAXV * 4, stream);
  hipMemsetAsync(out_coors, 0, ((size_t)MAXV * 3 + MAXV + 1) * sizeof(float), stream);

  int nb_ins  = (n + 256 * IB - 1) / (256 * IB);   // 977
  int nb_bkt  = (n + 256 * BB - 1) / (256 * BB);   // 1954
  int nb_scan = (n + CHUNK - 1) / CHUNK;           // 489 (<=512 required)

  k_insert<<<nb_ins, 256, 0, stream>>>(pts, ent, hslot, n);
  k_scan1<<<nb_scan, SCAN_BS, 0, stream>>>(hslot, (const u32*)ent, lead, blocksums, n);
  k_scan2<<<1, 512, 0, stream>>>(blocksums, out_voxnum, lmax, nb_scan);
  k_scan3<<<nb_scan, SCAN_BS, 0, stream>>>(lead, hslot, (const u32*)ent, blocksums,
                                           out_coors, lmax, n);
  k_bucket<<<nb_bkt, 256, 0, stream>>>(lead, hslot /*rank*/, lmax, bcnt, bucket, n);
  k_emit<<<(MAXV + EMIT_SPB - 1) / EMIT_SPB, 256, 0, stream>>>(
      pts, bcnt, bucket, (float4*)out_voxels, out_npts);
}

// Round 6
// 270.353 us; speedup vs baseline: 1.2683x; 1.2683x over previous
//
#include <hip/hip_runtime.h>

// Deterministic hard voxelization (mmcv hard_voxelize_forward) for MI355X.
//
// v5: spatial binning + per-bin LDS hash table. No global hash table, no
// global random atomics. Leader ranks via a 2M-bit flag array + popcount
// prefix scan (exact Lmax pruning).
//
// Pipeline:
//   K1 k_bin   : point -> voxel lin -> bin=lin>>16 (1375 bins). Per-block LDS
//                histogram -> one global atomicAdd per bin to reserve ranges
//                -> scatter (lin,i) u64 pairs into fixed-cap bin regions.
//   K2 k_build : one block per bin. 4096-slot LDS hash {key,minidx} via LDS
//                CAS + LDS atomicMin. Writes Lvals[pos]=L per point (binned
//                order, streaming) and sets flag bit L for each distinct
//                voxel (atomicOr into 250KB bit array).
//   K3 k_rank  : single block: popcount prefix over 62500 flag words ->
//                wordpfx[], voxel_num, exact Lmax (first-index of the
//                rank-(MAXV-1) leader; INT_MAX if total<MAXV).
//   K4 k_keep  : stream binned pairs; L<=Lmax => r=rank(L) via wordpfx+popc;
//                append i to bucket[r]; leader (i==L) writes coors[r].
//   K5 k_emit  : 32 lanes/slot: rank-select bucket by original index, write
//                all 32 rows (zero-fill) + num_points.
//
// Rank logic: slot(v) = #voxels whose first point appears earlier
//           = #set flag bits below L(v). Keep slots < MAXV  <=>  L <= Lmax.
//
// Output (float32): voxels[120000*32*4] | coors[120000*3] | npts[120000] | voxel_num[1]

#define GX 1408
#define GY 1600
#define GZ 40
#define MAXV 120000
#define MAXP 32

#define BINSHIFT 16
#define NB 1375            // G_TOTAL = 90,112,000 = 1375 * 65536 exactly
#define BCAP 2048          // mean 1455/bin, sd ~38 -> 15 sigma headroom
#define TSIZE 4096         // LDS hash slots per bin (load <= 0.5)
#define TMASK (TSIZE - 1)

#define ABLK 512
#define APT 8              // points per thread in k_bin
#define EMIT_SPB 8         // 8 slots x 32 lanes = 256 threads

typedef unsigned long long u64;
typedef unsigned int u32;
#define EMPTY32 0xFFFFFFFFu

// ---------------------------------------------------------------- K1: bin
__global__ __launch_bounds__(ABLK) void k_bin(const float4* __restrict__ pts,
                                              u64* __restrict__ pairs,
                                              u32* __restrict__ bincnt, int n) {
  __shared__ u32 hist[NB];
  __shared__ u32 cursor[NB];
  int tid = threadIdx.x;
  for (int b = tid; b < NB; b += ABLK) hist[b] = 0;
  __syncthreads();

  int base0 = blockIdx.x * (ABLK * APT) + tid;
  int lin[APT];
#pragma unroll
  for (int j = 0; j < APT; ++j) {
    int i = base0 + j * ABLK;
    lin[j] = -1;
    if (i < n) {
      float4 p = pts[i];
      // Must match JAX f32 ops bit-exactly: (p - lo) / vs, floor, cast.
      int cx = (int)floorf((p.x - 0.0f)   / 0.05f);
      int cy = (int)floorf((p.y - -40.0f) / 0.05f);
      int cz = (int)floorf((p.z - -3.0f)  / 0.1f);
      if ((cx >= 0) && (cx < GX) && (cy >= 0) && (cy < GY) && (cz >= 0) && (cz < GZ)) {
        lin[j] = cz * (GX * GY) + cy * GX + cx;
        atomicAdd(&hist[(u32)lin[j] >> BINSHIFT], 1u);
      }
    }
  }
  __syncthreads();
  for (int b = tid; b < NB; b += ABLK) {
    u32 c = hist[b];
    cursor[b] = c ? atomicAdd(&bincnt[b], c) : 0u;
  }
  __syncthreads();
#pragma unroll
  for (int j = 0; j < APT; ++j) {
    if (lin[j] >= 0) {
      int i = base0 + j * ABLK;
      u32 b = (u32)lin[j] >> BINSHIFT;
      u32 pos = atomicAdd(&cursor[b], 1u);
      if (pos < BCAP) pairs[(size_t)b * BCAP + pos] = ((u64)(u32)lin[j] << 32) | (u32)i;
    }
  }
}

// -------------------------------------------------------------- K2: build
__global__ __launch_bounds__(256) void k_build(const u64* __restrict__ pairs,
                                               const u32* __restrict__ bincnt,
                                               u32* __restrict__ Lvals,
                                               u32* __restrict__ flag) {
  __shared__ u32 kk[TSIZE];
  __shared__ u32 mm[TSIZE];
  int tid = threadIdx.x;
  int b = blockIdx.x;
  for (int s = tid; s < TSIZE; s += 256) { kk[s] = EMPTY32; mm[s] = EMPTY32; }
  __syncthreads();

  u32 cnt = bincnt[b];
  if (cnt > BCAP) cnt = BCAP;
  size_t base = (size_t)b * BCAP;

  // Insert: LDS CAS claim + LDS atomicMin.
  for (u32 j = tid; j < cnt; j += 256) {
    u64 pr = pairs[base + j];
    u32 lin = (u32)(pr >> 32), i = (u32)pr;
    u32 s = (lin * 2654435761u) >> 20 & TMASK;
    while (true) {
      u32 old = atomicCAS(&kk[s], EMPTY32, lin);
      if (old == EMPTY32 || old == lin) break;
      s = (s + 1) & TMASK;
    }
    atomicMin(&mm[s], i);
  }
  __syncthreads();

  // Per-point leader value (lookup-only probe; table is final).
  for (u32 j = tid; j < cnt; j += 256) {
    u64 pr = pairs[base + j];
    u32 lin = (u32)(pr >> 32);
    u32 s = (lin * 2654435761u) >> 20 & TMASK;
    while (kk[s] != lin) s = (s + 1) & TMASK;
    Lvals[base + j] = mm[s];
  }
  // Leader flag bits (one per distinct voxel).
  for (int s = tid; s < TSIZE; s += 256) {
    if (kk[s] != EMPTY32) {
      u32 L = mm[s];
      atomicOr(&flag[L >> 5], 1u << (L & 31));
    }
  }
}

// --------------------------------------------------------------- K3: rank
// Single block, 1024 threads, 4 words per thread per chunk.
#define DW 4
__global__ __launch_bounds__(1024) void k_rank(const u32* __restrict__ flag,
                                               u32* __restrict__ wordpfx,
                                               float* __restrict__ voxnum_out,
                                               int* __restrict__ lmax, int nwords) {
  __shared__ u32 wsum[16];
  __shared__ u32 s_run;
  int tid = threadIdx.x;
  int lane = tid & 63, wid = tid >> 6;
  if (tid == 0) s_run = 0;
  __syncthreads();
  u32 run = 0;

  for (int w0 = 0; w0 < nwords; w0 += 1024 * DW) {
    int wb = w0 + tid * DW;
    u32 wd[DW], cc[DW], csum = 0;
#pragma unroll
    for (int k = 0; k < DW; ++k) {
      wd[k] = (wb + k < nwords) ? flag[wb + k] : 0u;
      cc[k] = __popc(wd[k]);
      csum += cc[k];
    }
    // wave64 inclusive scan of csum
    u32 incl = csum;
    for (int off = 1; off < 64; off <<= 1) {
      u32 v = __shfl_up(incl, off, 64);
      if (lane >= off) incl += v;
    }
    if (lane == 63) wsum[wid] = incl;
    __syncthreads();
    if (wid == 0 && lane < 16) {
      u32 x = wsum[lane];
      for (int off = 1; off < 16; off <<= 1) {
        u32 v = __shfl_up(x, off, 16);
        if (lane >= off) x += v;
      }
      wsum[lane] = x;  // inclusive over waves
    }
    __syncthreads();
    run = s_run;
    u32 wave_off = (wid > 0) ? wsum[wid - 1] : 0u;
    u32 p = run + wave_off + incl - csum;  // exclusive prefix at first word
#pragma unroll
    for (int k = 0; k < DW; ++k) {
      if (wb + k < nwords) {
        wordpfx[wb + k] = p;
        if (p < MAXV && p + cc[k] >= MAXV) {
          int kth = MAXV - 1 - (int)p;   // rank within this word
          u32 ww = wd[k];
          while (kth > 0) { ww &= ww - 1; --kth; }
          *lmax = ((wb + k) << 5) | (__ffs(ww) - 1);
        }
        p += cc[k];
      }
    }
    __syncthreads();
    if (tid == 1023) s_run = run + wsum[15];
    __syncthreads();
  }
  if (tid == 0) {
    u32 total = s_run;
    *voxnum_out = (float)(total < MAXV ? total : (u32)MAXV);
    if (total < MAXV) *lmax = 0x7FFFFFFF;
  }
}

// --------------------------------------------------------------- K4: keep
__global__ __launch_bounds__(256) void k_keep(const u64* __restrict__ pairs,
                                              const u32* __restrict__ bincnt,
                                              const u32* __restrict__ Lvals,
                                              const u32* __restrict__ flag,
                                              const u32* __restrict__ wordpfx,
                                              const int* __restrict__ lmaxp,
                                              int* __restrict__ bcnt,
                                              int* __restrict__ bucket,
                                              float* __restrict__ out_coors) {
  int tid = threadIdx.x;
  int b = blockIdx.x;
  u32 Lmax = (u32)*lmaxp;
  u32 cnt = bincnt[b];
  if (cnt > BCAP) cnt = BCAP;
  size_t base = (size_t)b * BCAP;

  for (u32 j = tid; j < cnt; j += 256) {
    u32 L = Lvals[base + j];
    if (L > Lmax) continue;                 // rank(L) >= MAXV
    u64 pr = pairs[base + j];
    u32 lin = (u32)(pr >> 32), i = (u32)pr;
    u32 w = L >> 5;
    u32 r = wordpfx[w] + __popc(flag[w] & ((1u << (L & 31)) - 1u));
    int pos = atomicAdd(&bcnt[r], 1);
    if (pos < MAXP) bucket[r * MAXP + pos] = (int)i;
    if (i == L) {                            // unique leader writes coors
      int li = (int)lin;
      int x = li % GX;
      int t = li / GX;
      int y = t % GY;
      int z = t / GY;
      out_coors[r * 3 + 0] = (float)z;
      out_coors[r * 3 + 1] = (float)y;
      out_coors[r * 3 + 2] = (float)x;
    }
  }
}

// --------------------------------------------------------------- K5: emit
// 32 lanes/slot; lane r rank-selects bucket entry of rank r (ascending
// original index); writes all 32 rows (zero-fill). Coalesced 16B stores.
__global__ __launch_bounds__(256) void k_emit(const float4* __restrict__ pts,
                                              const int* __restrict__ bcnt,
                                              const int* __restrict__ bucket,
                                              float4* __restrict__ out_voxels,
                                              float* __restrict__ out_npts) {
  __shared__ int sb[EMIT_SPB][MAXP];
  int grp = threadIdx.x >> 5;
  int r = threadIdx.x & 31;
  int s = blockIdx.x * EMIT_SPB + grp;
  if (s >= MAXV) return;

  int nfull = bcnt[s];
  int m = nfull < MAXP ? nfull : MAXP;
  if (r < m) sb[grp][r] = bucket[s * MAXP + r];
  __syncthreads();

  float4 row = make_float4(0.f, 0.f, 0.f, 0.f);
  if (r < m) {
    int mine = -1;
    for (int jj = 0; jj < m; ++jj) {   // entries unique; find rank==r
      int ej = sb[grp][jj];
      int rk = 0;
      for (int kk2 = 0; kk2 < m; ++kk2) rk += (sb[grp][kk2] < ej) ? 1 : 0;
      if (rk == r) mine = ej;
    }
    row = pts[mine];
  }
  out_voxels[(size_t)s * MAXP + r] = row;
  if (r == 0) out_npts[s] = (float)m;
}

extern "C" void kernel_launch(void* const* d_in, const int* in_sizes, int n_in,
                              void* d_out, int out_size, void* d_ws, size_t ws_size,
                              hipStream_t stream) {
  const float4* pts = (const float4*)d_in[0];
  int n = in_sizes[0] / 4;  // 2,000,000
  float* out = (float*)d_out;
  int nwords = (n + 31) / 32;  // 62500

  // Workspace layout (bytes); total ~50.2 MB
  char* ws = (char*)d_ws;
  size_t off = 0;
  u64* pairs   = (u64*)(ws + off); off += (size_t)NB * BCAP * 8;   // 22.53 MB
  u32* Lvals   = (u32*)(ws + off); off += (size_t)NB * BCAP * 4;   // 11.26 MB
  u32* flag    = (u32*)(ws + off); off += 262144;                  // 250 KB used
  u32* wordpfx = (u32*)(ws + off); off += 262144;                  // 250 KB used
  u32* bincnt  = (u32*)(ws + off); off += 8192;                    // 5.5 KB used
  int* lmax    = (int*)(ws + off); off += 64;
  int* bcnt    = (int*)(ws + off); off += (size_t)MAXV * 4;        // 480 KB
  int* bucket  = (int*)(ws + off); off += (size_t)MAXV * MAXP * 4; // 15.36 MB

  float* out_voxels = out;                                     // 120000*32*4
  float* out_coors  = out + (size_t)MAXV * MAXP * 4;           // 120000*3
  float* out_npts   = out_coors + (size_t)MAXV * 3;            // 120000
  // voxel_num = out_npts + MAXV (written by k_rank)

  hipMemsetAsync(bincnt, 0, 8192, stream);
  hipMemsetAsync(flag, 0, (size_t)nwords * 4, stream);
  hipMemsetAsync(bcnt, 0, (size_t)MAXV * 4, stream);
  hipMemsetAsync(out_coors, 0, ((size_t)MAXV * 3 + MAXV + 1) * sizeof(float), stream);

  int nb_bin = (n + ABLK * APT - 1) / (ABLK * APT);  // 489

  k_bin<<<nb_bin, ABLK, 0, stream>>>(pts, pairs, bincnt, n);
  k_build<<<NB, 256, 0, stream>>>(pairs, bincnt, Lvals, flag);
  k_rank<<<1, 1024, 0, stream>>>(flag, wordpfx, out_npts + MAXV, lmax, nwords);
  k_keep<<<NB, 256, 0, stream>>>(pairs, bincnt, Lvals, flag, wordpfx, lmax,
                                 bcnt, bucket, out_coors);
  k_emit<<<(MAXV + EMIT_SPB - 1) / EMIT_SPB, 256, 0, stream>>>(
      pts, bcnt, bucket, (float4*)out_voxels, out_npts);
}

// Round 7
// 175.785 us; speedup vs baseline: 1.9506x; 1.5380x over previous
//
#include <hip/hip_runtime.h>

// Deterministic hard voxelization (mmcv hard_voxelize_forward) for MI355X.
//
// v6: per-bin u64 LDS hash (single CAS claims key+min); leader flags via
// non-atomic byte array (global atomics were write-through: 69.5MB observed
// for 2M atomicOr) -> byte->bit conversion kernel; 3-kernel rank scan.
//
// Pipeline:
//   K1 k_bin   : point -> lin -> bin=lin>>15 (2750 bins). LDS histogram ->
//                one global atomicAdd/bin to reserve -> scatter (lin,i) u64.
//   K2 k_build : one block per bin. 2048-slot LDS hash, u64 {lin,min} single
//                CAS claim + CAS-min for dupes. Lvals[pos]=L streaming;
//                leaders write isleader[L]=1 (unique owner, non-atomic).
//   K3 k_rankA : bytes->bit words (single writer/word) + block popc sums.
//   K4 k_rankB : 1 block: exclusive scan of 245 block sums; voxel_num; lmax
//                = INT_MAX if total < MAXV.
//   K5 k_rankC : re-scan: wordpfx[w] = rank at word start; crossing word
//                selects exact Lmax (first-index of rank MAXV-1 leader).
//   K6 k_keep  : stream pairs; L<=Lmax => r=wordpfx+popc; append bucket;
//                leader writes coors[r]=(z,y,x).
//   K7 k_emit  : 32 lanes/slot: rank-select by original index, write all
//                32 rows (zero-fill) + num_points.
//
// Output (float32): voxels[120000*32*4] | coors[120000*3] | npts[120000] | voxel_num[1]

#define GX 1408
#define GY 1600
#define GZ 40
#define MAXV 120000
#define MAXP 32

#define BINSHIFT 15
#define NB 2750            // 90,112,000 = 2750 * 32768 exactly
#define BCAP 1024          // mean 727/bin, sd ~27 -> 11 sigma headroom
#define TSIZE 2048         // LDS hash slots (load ~0.36), u64 -> 16 KB
#define TMASK (TSIZE - 1)
#define PB 4               // pair preload batch in k_build

#define ABLK 512
#define APT 16             // points per thread in k_bin (245 blocks)
#define EMIT_SPB 8

typedef unsigned long long u64;
typedef unsigned int u32;
#define EMPTY64 0xFFFFFFFFFFFFFFFFull

__device__ __forceinline__ u32 hashw(u32 lin) {
  return (lin * 2654435761u) >> 21 & TMASK;   // top 11 bits of product
}

// ---------------------------------------------------------------- K1: bin
__global__ __launch_bounds__(ABLK) void k_bin(const float4* __restrict__ pts,
                                              u64* __restrict__ pairs,
                                              u32* __restrict__ bincnt, int n) {
  __shared__ u32 hist[NB];
  __shared__ u32 cursor[NB];
  int tid = threadIdx.x;
  for (int b = tid; b < NB; b += ABLK) hist[b] = 0;
  __syncthreads();

  int base0 = blockIdx.x * (ABLK * APT) + tid;
  int lin[APT];
#pragma unroll
  for (int j = 0; j < APT; ++j) {
    int i = base0 + j * ABLK;
    lin[j] = -1;
    if (i < n) {
      float4 p = pts[i];
      // Must match JAX f32 ops bit-exactly: (p - lo) / vs, floor, cast.
      int cx = (int)floorf((p.x - 0.0f)   / 0.05f);
      int cy = (int)floorf((p.y - -40.0f) / 0.05f);
      int cz = (int)floorf((p.z - -3.0f)  / 0.1f);
      if ((cx >= 0) && (cx < GX) && (cy >= 0) && (cy < GY) && (cz >= 0) && (cz < GZ)) {
        lin[j] = cz * (GX * GY) + cy * GX + cx;
        atomicAdd(&hist[(u32)lin[j] >> BINSHIFT], 1u);
      }
    }
  }
  __syncthreads();
  for (int b = tid; b < NB; b += ABLK) {
    u32 c = hist[b];
    cursor[b] = c ? atomicAdd(&bincnt[b], c) : 0u;
  }
  __syncthreads();
#pragma unroll
  for (int j = 0; j < APT; ++j) {
    if (lin[j] >= 0) {
      int i = base0 + j * ABLK;
      u32 b = (u32)lin[j] >> BINSHIFT;
      u32 pos = atomicAdd(&cursor[b], 1u);
      if (pos < BCAP) pairs[(size_t)b * BCAP + pos] = ((u64)(u32)lin[j] << 32) | (u32)i;
    }
  }
}

// -------------------------------------------------------------- K2: build
__global__ __launch_bounds__(256) void k_build(const u64* __restrict__ pairs,
                                               const u32* __restrict__ bincnt,
                                               u32* __restrict__ Lvals,
                                               unsigned char* __restrict__ isleader) {
  __shared__ u64 tab[TSIZE];
  int tid = threadIdx.x;
  int b = blockIdx.x;
  for (int s = tid; s < TSIZE; s += 256) tab[s] = EMPTY64;
  __syncthreads();

  u32 cnt = bincnt[b];
  if (cnt > BCAP) cnt = BCAP;
  size_t base = (size_t)b * BCAP;

  // Insert: one u64 LDS CAS claims {key, min}; resolve handles dupes/probes.
  for (u32 c0 = 0; c0 < cnt; c0 += 256u * PB) {
    u64 pr[PB]; u32 hh[PB]; u64 old[PB];
#pragma unroll
    for (int k = 0; k < PB; ++k) {
      u32 idx = c0 + tid + (u32)k * 256u;
      pr[k] = (idx < cnt) ? pairs[base + idx] : EMPTY64;
    }
#pragma unroll
    for (int k = 0; k < PB; ++k) {
      if (pr[k] != EMPTY64) {
        hh[k] = hashw((u32)(pr[k] >> 32));
        old[k] = atomicCAS(&tab[hh[k]], EMPTY64, pr[k]);
      }
    }
#pragma unroll
    for (int k = 0; k < PB; ++k) {
      if (pr[k] != EMPTY64) {
        u32 lin = (u32)(pr[k] >> 32), i = (u32)pr[k];
        u32 s = hh[k];
        u64 o = old[k];
        while (o != EMPTY64) {
          if ((u32)(o >> 32) == lin) {              // same key: CAS-min low word
            while ((u32)o > i) {
              u64 want = (o & 0xFFFFFFFF00000000ull) | (u64)i;
              u64 prev = atomicCAS(&tab[s], o, want);
              if (prev == o) break;
              o = prev;
            }
            break;
          }
          s = (s + 1) & TMASK;                       // probe on
          o = atomicCAS(&tab[s], EMPTY64, pr[k]);
        }
      }
    }
  }
  __syncthreads();

  // Lookup (table final): per-point leader value + leader byte.
  for (u32 c0 = 0; c0 < cnt; c0 += 256u * PB) {
    u64 pr[PB];
#pragma unroll
    for (int k = 0; k < PB; ++k) {
      u32 idx = c0 + tid + (u32)k * 256u;
      pr[k] = (idx < cnt) ? pairs[base + idx] : EMPTY64;
    }
#pragma unroll
    for (int k = 0; k < PB; ++k) {
      if (pr[k] != EMPTY64) {
        u32 idx = c0 + tid + (u32)k * 256u;
        u32 lin = (u32)(pr[k] >> 32), i = (u32)pr[k];
        u32 s = hashw(lin);
        u64 e = tab[s];
        while ((u32)(e >> 32) != lin) { s = (s + 1) & TMASK; e = tab[s]; }
        u32 L = (u32)e;
        Lvals[base + idx] = L;
        if (L == i) isleader[i] = 1;   // unique owner; array pre-zeroed
      }
    }
  }
}

// ------------------------------------------------------------- K3: rankA
// One thread per 32-point word: bytes -> bits (single writer) + popc sums.
__global__ __launch_bounds__(256) void k_rankA(const unsigned char* __restrict__ isl,
                                               u32* __restrict__ flag,
                                               u32* __restrict__ bsum, int nwords) {
  __shared__ u32 red[256];
  int t = threadIdx.x;
  int w = blockIdx.x * 256 + t;
  u32 bits = 0;
  if (w < nwords) {
    const uint4* p = (const uint4*)(isl + (size_t)w * 32);
    uint4 a = p[0], b4 = p[1];
    u32 wd[8] = {a.x, a.y, a.z, a.w, b4.x, b4.y, b4.z, b4.w};
#pragma unroll
    for (int k = 0; k < 8; ++k) {
      u32 v = wd[k];
      bits |= (((v >> 0) & 1u) | ((v >> 8) & 1u) << 1 |
               ((v >> 16) & 1u) << 2 | ((v >> 24) & 1u) << 3) << (4 * k);
    }
    flag[w] = bits;
  }
  red[t] = __popc(bits);
  __syncthreads();
  for (int off = 128; off > 0; off >>= 1) {
    if (t < off) red[t] += red[t + off];
    __syncthreads();
  }
  if (t == 0) bsum[blockIdx.x] = red[0];
}

// ------------------------------------------------------------- K4: rankB
__global__ __launch_bounds__(256) void k_rankB(u32* __restrict__ bsum,
                                               float* __restrict__ voxnum_out,
                                               int* __restrict__ lmax, int nbk) {
  __shared__ u32 sm[256];
  int t = threadIdx.x;
  u32 v = (t < nbk) ? bsum[t] : 0;
  sm[t] = v;
  __syncthreads();
  for (int off = 1; off < 256; off <<= 1) {
    u32 x = sm[t];
    u32 add = (t >= off) ? sm[t - off] : 0;
    __syncthreads();
    sm[t] = x + add;
    __syncthreads();
  }
  if (t < nbk) bsum[t] = sm[t] - v;  // exclusive block offsets
  if (t == 255) {
    u32 total = sm[255];
    *voxnum_out = (float)(total < MAXV ? total : (u32)MAXV);
    if (total < MAXV) *lmax = 0x7FFFFFFF;  // else k_rankC's crossing writes
  }
}

// ------------------------------------------------------------- K5: rankC
__global__ __launch_bounds__(256) void k_rankC(const u32* __restrict__ flag,
                                               const u32* __restrict__ bsum,
                                               u32* __restrict__ wordpfx,
                                               int* __restrict__ lmax, int nwords) {
  __shared__ u32 sm[256];
  int t = threadIdx.x;
  int w = blockIdx.x * 256 + t;
  u32 bits = (w < nwords) ? flag[w] : 0u;
  u32 c = __popc(bits);
  sm[t] = c;
  __syncthreads();
  for (int off = 1; off < 256; off <<= 1) {
    u32 x = sm[t];
    u32 add = (t >= off) ? sm[t - off] : 0;
    __syncthreads();
    sm[t] = x + add;
    __syncthreads();
  }
  u32 p = bsum[blockIdx.x] + sm[t] - c;  // exclusive rank at word start
  if (w < nwords) {
    wordpfx[w] = p;
    if (p < MAXV && p + c >= MAXV) {     // word containing rank MAXV-1
      int kth = MAXV - 1 - (int)p;
      u32 ww = bits;
      while (kth > 0) { ww &= ww - 1; --kth; }
      *lmax = (w << 5) | (__ffs(ww) - 1);
    }
  }
}

// --------------------------------------------------------------- K6: keep
__global__ __launch_bounds__(256) void k_keep(const u64* __restrict__ pairs,
                                              const u32* __restrict__ bincnt,
                                              const u32* __restrict__ Lvals,
                                              const u32* __restrict__ flag,
                                              const u32* __restrict__ wordpfx,
                                              const int* __restrict__ lmaxp,
                                              int* __restrict__ bcnt,
                                              int* __restrict__ bucket,
                                              float* __restrict__ out_coors) {
  int tid = threadIdx.x;
  int b = blockIdx.x;
  u32 Lmax = (u32)*lmaxp;
  u32 cnt = bincnt[b];
  if (cnt > BCAP) cnt = BCAP;
  size_t base = (size_t)b * BCAP;

  for (u32 j = tid; j < cnt; j += 256) {
    u32 L = Lvals[base + j];
    if (L > Lmax) continue;                 // rank(L) >= MAXV
    u64 pr = pairs[base + j];
    u32 lin = (u32)(pr >> 32), i = (u32)pr;
    u32 w = L >> 5;
    u32 r = wordpfx[w] + __popc(flag[w] & ((1u << (L & 31)) - 1u));
    int pos = atomicAdd(&bcnt[r], 1);
    if (pos < MAXP) bucket[r * MAXP + pos] = (int)i;
    if (i == L) {                            // unique leader writes coors
      int li = (int)lin;
      int x = li % GX;
      int t2 = li / GX;
      int y = t2 % GY;
      int z = t2 / GY;
      out_coors[r * 3 + 0] = (float)z;
      out_coors[r * 3 + 1] = (float)y;
      out_coors[r * 3 + 2] = (float)x;
    }
  }
}

// --------------------------------------------------------------- K7: emit
__global__ __launch_bounds__(256) void k_emit(const float4* __restrict__ pts,
                                              const int* __restrict__ bcnt,
                                              const int* __restrict__ bucket,
                                              float4* __restrict__ out_voxels,
                                              float* __restrict__ out_npts) {
  __shared__ int sb[EMIT_SPB][MAXP];
  int grp = threadIdx.x >> 5;
  int r = threadIdx.x & 31;
  int s = blockIdx.x * EMIT_SPB + grp;
  if (s >= MAXV) return;

  int nfull = bcnt[s];
  int m = nfull < MAXP ? nfull : MAXP;
  if (r < m) sb[grp][r] = bucket[s * MAXP + r];
  __syncthreads();

  float4 row = make_float4(0.f, 0.f, 0.f, 0.f);
  if (r < m) {
    int mine = -1;
    for (int jj = 0; jj < m; ++jj) {   // entries unique; find rank==r
      int ej = sb[grp][jj];
      int rk = 0;
      for (int kk2 = 0; kk2 < m; ++kk2) rk += (sb[grp][kk2] < ej) ? 1 : 0;
      if (rk == r) mine = ej;
    }
    row = pts[mine];
  }
  out_voxels[(size_t)s * MAXP + r] = row;
  if (r == 0) out_npts[s] = (float)m;
}

extern "C" void kernel_launch(void* const* d_in, const int* in_sizes, int n_in,
                              void* d_out, int out_size, void* d_ws, size_t ws_size,
                              hipStream_t stream) {
  const float4* pts = (const float4*)d_in[0];
  int n = in_sizes[0] / 4;  // 2,000,000
  float* out = (float*)d_out;
  int nwords = (n + 31) / 32;            // 62500
  int nbk = (nwords + 255) / 256;        // 245 (must be <=256)

  // Workspace layout (bytes); total ~49.8 MB
  char* ws = (char*)d_ws;
  size_t off = 0;
  u64* pairs    = (u64*)(ws + off); off += (size_t)NB * BCAP * 8;   // 22.53 MB
  u32* Lvals    = (u32*)(ws + off); off += (size_t)NB * BCAP * 4;   // 11.26 MB
  unsigned char* isleader = (unsigned char*)(ws + off); off += (size_t)n; // 2 MB
  u32* flag     = (u32*)(ws + off); off += 262144;
  u32* wordpfx  = (u32*)(ws + off); off += 262144;
  u32* bsum     = (u32*)(ws + off); off += 1024;
  u32* bincnt   = (u32*)(ws + off); off += 16384;
  int* lmax     = (int*)(ws + off); off += 64;
  int* bcnt     = (int*)(ws + off); off += (size_t)MAXV * 4;        // 480 KB
  int* bucket   = (int*)(ws + off); off += (size_t)MAXV * MAXP * 4; // 15.36 MB

  float* out_voxels = out;                                     // 120000*32*4
  float* out_coors  = out + (size_t)MAXV * MAXP * 4;           // 120000*3
  float* out_npts   = out_coors + (size_t)MAXV * 3;            // 120000
  // voxel_num = out_npts + MAXV (written by k_rankB)

  hipMemsetAsync(bincnt, 0, 16384, stream);
  hipMemsetAsync(isleader, 0, (size_t)n, stream);
  hipMemsetAsync(bcnt, 0, (size_t)MAXV * 4, stream);
  hipMemsetAsync(out_coors, 0, ((size_t)MAXV * 3 + MAXV + 1) * sizeof(float), stream);

  int nb_bin = (n + ABLK * APT - 1) / (ABLK * APT);  // 245

  k_bin<<<nb_bin, ABLK, 0, stream>>>(pts, pairs, bincnt, n);
  k_build<<<NB, 256, 0, stream>>>(pairs, bincnt, Lvals, isleader);
  k_rankA<<<nbk, 256, 0, stream>>>(isleader, flag, bsum, nwords);
  k_rankB<<<1, 256, 0, stream>>>(bsum, out_npts + MAXV, lmax, nbk);
  k_rankC<<<nbk, 256, 0, stream>>>(flag, bsum, wordpfx, lmax, nwords);
  k_keep<<<NB, 256, 0, stream>>>(pairs, bincnt, Lvals, flag, wordpfx, lmax,
                                 bcnt, bucket, out_coors);
  k_emit<<<(MAXV + EMIT_SPB - 1) / EMIT_SPB, 256, 0, stream>>>(
      pts, bcnt, bucket, (float4*)out_voxels, out_npts);
}